// Round 10
// baseline (393.776 us; speedup 1.0000x reference)
//
#include <hip/hip_runtime.h>
#include <hip/hip_bf16.h>

typedef short bf16x8 __attribute__((ext_vector_type(8)));
typedef float f32x4 __attribute__((ext_vector_type(4)));

#define HD 512     // H*D
#define KDIM 512   // IN_DIM == H*D == 512
#define NHEAD 4
#define DHEAD 128
#define C1CAP 1024     // capacity for F1 = srcs(ids)   (~530)
#define C2CAP 16384    // capacity for F2 = srcs(F1)    (~14.8k)
#define E1CAP 2048     // edges into ids (~530)
#define E2CAP 32768    // edges into F1 (~17.5k)
#define GA 448         // persistent grid: 1.75 blocks/CU at launch_bounds(256,2)
                       // -> 64 residency slots of headroom (R3's 512@2/CU had 0)

struct PassSM {
    unsigned bm[1568];     // per-block node bitmap (N=50000 -> 1563 words)
    int2 eBuf[256];
    int fBuf[256];
    int sid[16];
    int eCnt, fCnt, eBase, fBase;
};
struct ScatSM { int soff[1024]; int sc[256]; int s1[16]; };
struct GemmSM {
    __hip_bfloat16 As[128][40];
    __hip_bfloat16 Bs[128][40];
    float pel[2][128];
    float perr[2][128];
};
union SMem {
    PassSM pass;
    float tile[64][65];    // transpose tile (+1 pad -> conflict-free column reads)
    ScatSM scat;
    GemmSM gemm;
    int s_c;
};

struct Args {
    const void* features;
    const void* W0; const void* W1;
    __hip_bfloat16* Wt0; __hip_bfloat16* Wt1;
    const void* sp0; const void* sp1; const void* sp2;
    const void* sp3; const void* sp4; const void* sp5;
    float* smallc;
    const int* ids; int B;
    const int* src; const int* dst; int E;
    int* mapId; int* map1; int* map2;
    int2* E1l; int2* E2l; int* F1list; int* F2list;
    int* counters;              // [0]nE1 [1]nE2 [2]nF1 [3]nF2
    int* cnt1; int* cnt2;
    int* arrive; int* rel;      // GA ints each, zeroed per replay
    int* off1; int* off2; int* b1; int* b2;
    __hip_bfloat16* Ac; __hip_bfloat16* ft0c; __hip_bfloat16* h1c; __hip_bfloat16* ft1c;
    float* el0; float* er0; float* el1; float* er1;
    void* out;
};

// ---------------- grid barrier: RELAXED polls + one fence per barrier ----------------
// R5-validated (288us kernel, passed): relaxed polls (no per-iteration cache
// maintenance -- R1/R4's ~90us/barrier was ACQUIRE-per-poll invalidates),
// single release fence before arrival, single acquire fence after wait.
// Range-guarded for GA=448 (polling an unset flag would hang).
__device__ __forceinline__ void gbar(const Args& a, int gen) {
    __syncthreads();
    const int t = threadIdx.x;
    if (blockIdx.x == 0) {
        if (t > 0) {
            while (__hip_atomic_load(&a.arrive[t], __ATOMIC_RELAXED, __HIP_MEMORY_SCOPE_AGENT) < gen)
                __builtin_amdgcn_s_sleep(1);
        }
        if (t + 256 < GA) {
            while (__hip_atomic_load(&a.arrive[t + 256], __ATOMIC_RELAXED, __HIP_MEMORY_SCOPE_AGENT) < gen)
                __builtin_amdgcn_s_sleep(1);
        }
        __builtin_amdgcn_fence(__ATOMIC_ACQUIRE, "agent");   // sync with all producers
        __syncthreads();
        __builtin_amdgcn_fence(__ATOMIC_RELEASE, "agent");   // forward visibility
        if (t > 0)
            __hip_atomic_store(&a.rel[t], gen, __ATOMIC_RELAXED, __HIP_MEMORY_SCOPE_AGENT);
        if (t + 256 < GA)
            __hip_atomic_store(&a.rel[t + 256], gen, __ATOMIC_RELAXED, __HIP_MEMORY_SCOPE_AGENT);
    } else {
        if (t == 0) {
            __builtin_amdgcn_fence(__ATOMIC_RELEASE, "agent");
            __hip_atomic_store(&a.arrive[blockIdx.x], gen, __ATOMIC_RELAXED, __HIP_MEMORY_SCOPE_AGENT);
            while (__hip_atomic_load(&a.rel[blockIdx.x], __ATOMIC_RELAXED, __HIP_MEMORY_SCOPE_AGENT) < gen)
                __builtin_amdgcn_s_sleep(16);
            __builtin_amdgcn_fence(__ATOMIC_ACQUIRE, "agent");
        }
        __syncthreads();
    }
}

// ---------------- per-block dtype detect (1 = bf16, 0 = f32) ----------------
__device__ int detect_bf16(const unsigned short* f, int* s_c) {
    int c = 0;
#pragma unroll
    for (int k = 0; k < 4; ++k) {
        unsigned short u = f[2 * (threadIdx.x + k * 256)];
        int e = (u >> 7) & 0xFF;
        c += (e >= 96 && e <= 140) ? 1 : 0;
    }
#pragma unroll
    for (int off = 32; off; off >>= 1) c += __shfl_xor(c, off, 64);
    if (threadIdx.x == 0) *s_c = 0;
    __syncthreads();
    if ((threadIdx.x & 63) == 0) atomicAdd(s_c, c);
    __syncthreads();
    int r = (*s_c > 512) ? 1 : 0;
    __syncthreads();   // union reuse safety
    return r;
}

// ---------------- BFS scan (LDS bitmap + block-buffered compaction, grid-strided) ----
// Emits edges with PACKED within-bucket position: v.y = slot | (p << SHIFT),
// so the later scatter is cursor-free and embarrassingly parallel.
// MODE 0: slot = index of d in sid[] (pass 1).  MODE 1: slot = map1g[d].
template<int MODE>
__device__ void pass_scan(const int* __restrict__ src, const int* __restrict__ dst,
                          int E, int B, const int* __restrict__ map1g, PassSM& sm,
                          int2* __restrict__ elist, int* ecnt, int ecap,
                          int* __restrict__ cntArr,
                          int* __restrict__ mapm, int* __restrict__ Flist,
                          int* nFr, int fcap) {
    const int t = threadIdx.x;
    const int nq = E >> 2;   // E % 4 == 0
    for (int gid = blockIdx.x * 256 + t; gid < nq; gid += GA * 256) {
        const int4 d4 = ((const int4*)dst)[gid];
        const int dv[4] = {d4.x, d4.y, d4.z, d4.w};
#pragma unroll
        for (int k = 0; k < 4; ++k) {
            const int d = dv[k];
            if ((sm.bm[d >> 5] >> (d & 31)) & 1u) {
                const int e = 4 * gid + k;
                int slot;
                if (MODE == 0) {
                    slot = 0;
                    for (int q = 0; q < B; ++q) if (sm.sid[q] == d) slot = q;
                } else {
                    slot = map1g[d]; if (slot < 0) slot = 0;
                }
                int p = atomicAdd(&cntArr[slot], 1);   // position within bucket
                int2 v; v.x = src[e]; v.y = slot | (p << (MODE == 0 ? 4 : 10));
                int pp = atomicAdd(&sm.eCnt, 1);
                if (pp < 256) sm.eBuf[pp] = v;
                else { int q = atomicAdd(ecnt, 1); if (q < ecap) elist[q] = v; }
                const int s = v.x;
                if (atomicCAS(&mapm[s], -1, -2) == -1) {
                    int q = atomicAdd(&sm.fCnt, 1);
                    if (q < 256) sm.fBuf[q] = s;
                    else {
                        int g2 = atomicAdd(nFr, 1);
                        if (g2 < fcap) { Flist[g2] = s; mapm[s] = g2; }
                        else mapm[s] = 0;
                    }
                }
            }
        }
    }
    __syncthreads();
    const int ne = (sm.eCnt < 256) ? sm.eCnt : 256;
    const int nf = (sm.fCnt < 256) ? sm.fCnt : 256;
    if (t == 0 && ne) sm.eBase = atomicAdd(ecnt, ne);
    if (t == 64 && nf) sm.fBase = atomicAdd(nFr, nf);
    __syncthreads();
    for (int i = t; i < ne; i += 256) {
        int pos = sm.eBase + i;
        if (pos < ecap) elist[pos] = sm.eBuf[i];
    }
    for (int i = t; i < nf; i += 256) {
        int q = sm.fBase + i; int s = sm.fBuf[i];
        if (q < fcap) { Flist[q] = s; mapm[s] = q; }
        else mapm[s] = 0;
    }
}

// ---------------- GEMM tile + fused el/er epilogue, reg-prefetched staging ----------------
__device__ void gemm_tile(const __hip_bfloat16* __restrict__ A,
                          const __hip_bfloat16* __restrict__ Bt,
                          __hip_bfloat16* __restrict__ C,
                          const float* __restrict__ al_, const float* __restrict__ ar_,
                          float* __restrict__ el, float* __restrict__ er,
                          int cntv, int m0, int n0, GemmSM& sm) {
    const int t = threadIdx.x;
    const int lane = t & 63, wave = t >> 6;
    const int wm = (wave >> 1) * 64, wn = (wave & 1) * 64;
    const int fr = lane & 15, fk = (lane >> 4) * 8;
    const int r0 = t >> 2;
    const int c0 = (t & 3) * 8;

    int arow[2];
#pragma unroll
    for (int r = 0; r < 2; ++r) {
        int rr = m0 + r * 64 + r0;
        if (rr >= cntv) rr = cntv - 1;
        arow[r] = rr;
    }

    auto loadAB = [&](int kt, uint4 va[2], uint4 vb[2]) {
#pragma unroll
        for (int r = 0; r < 2; ++r) {
            va[r] = *(const uint4*)&A[(size_t)arow[r] * KDIM + kt + c0];
            int row = r * 64 + r0;
            vb[r] = *(const uint4*)&Bt[(size_t)(n0 + row) * KDIM + kt + c0];
        }
    };

    f32x4 acc[4][4];
#pragma unroll
    for (int i = 0; i < 4; ++i)
#pragma unroll
        for (int j = 0; j < 4; ++j)
#pragma unroll
            for (int r = 0; r < 4; ++r) acc[i][j][r] = 0.f;

    uint4 cva[2], cvb[2], nva[2], nvb[2];
    loadAB(0, cva, cvb);
    for (int kt = 0; kt < KDIM; kt += 32) {
#pragma unroll
        for (int r = 0; r < 2; ++r) {
            int row = r * 64 + r0;
            *(uint4*)&sm.As[row][c0] = cva[r];
            *(uint4*)&sm.Bs[row][c0] = cvb[r];
        }
        __syncthreads();
        if (kt + 32 < KDIM) loadAB(kt + 32, nva, nvb);   // overlaps MFMA below
        bf16x8 af[4], bfr[4];
#pragma unroll
        for (int i = 0; i < 4; ++i) af[i]  = *(const bf16x8*)&sm.As[wm + i * 16 + fr][fk];
#pragma unroll
        for (int j = 0; j < 4; ++j) bfr[j] = *(const bf16x8*)&sm.Bs[wn + j * 16 + fr][fk];
#pragma unroll
        for (int i = 0; i < 4; ++i)
#pragma unroll
            for (int j = 0; j < 4; ++j)
                acc[i][j] = __builtin_amdgcn_mfma_f32_16x16x32_bf16(af[i], bfr[j], acc[i][j], 0, 0, 0);
        __syncthreads();
#pragma unroll
        for (int r = 0; r < 2; ++r) { cva[r] = nva[r]; cvb[r] = nvb[r]; }
    }

    const int cr = (lane >> 4) * 4;
    const int cc = lane & 15;
#pragma unroll
    for (int i = 0; i < 4; ++i)
#pragma unroll
        for (int j = 0; j < 4; ++j)
#pragma unroll
            for (int rg = 0; rg < 4; ++rg) {
                int m = m0 + wm + i * 16 + cr + rg;
                int n = n0 + wn + j * 16 + cc;
                C[(size_t)m * HD + n] = __float2bfloat16(acc[i][j][rg]);
            }

    // fused el/er (head h = n0>>7; block owns the full head slice of these rows)
    const int h = n0 >> 7;
    float alv[4], arv[4];
#pragma unroll
    for (int j = 0; j < 4; ++j) {
        alv[j] = al_[h * DHEAD + wn + j * 16 + cc];
        arv[j] = ar_[h * DHEAD + wn + j * 16 + cc];
    }
#pragma unroll
    for (int i = 0; i < 4; ++i)
#pragma unroll
        for (int rg = 0; rg < 4; ++rg) {
            float sl = 0.f, sr = 0.f;
#pragma unroll
            for (int j = 0; j < 4; ++j) {
                float c = acc[i][j][rg];
                sl += c * alv[j];
                sr += c * arv[j];
            }
#pragma unroll
            for (int off = 1; off < 16; off <<= 1) {
                sl += __shfl_xor(sl, off, 16);
                sr += __shfl_xor(sr, off, 16);
            }
            if (cc == 0) {
                int row = wm + i * 16 + cr + rg;
                sm.pel[wn >> 6][row] = sl;
                sm.perr[wn >> 6][row] = sr;
            }
        }
    __syncthreads();
    if (t < 128) {
        int m = m0 + t;
        if (m < cntv) {
            el[m * NHEAD + h] = sm.pel[0][t] + sm.pel[1][t];
            er[m * NHEAD + h] = sm.perr[0][t] + sm.perr[1][t];
        }
    }
    __syncthreads();   // protect pel/perr (and As/Bs) before next tile
}

// ---------------- the whole pipeline, one launch, 6 cheap barriers ----------------
__global__ __launch_bounds__(256, 2) void fused_all(Args a) {
    __shared__ alignas(16) SMem sm;
    const int t = threadIdx.x;
    const int bid = blockIdx.x;
    int gen = 0;

    const int isbf = detect_bf16((const unsigned short*)a.features, &sm.s_c);

    // ---- P0: prep (tiled transpose / smalls / setid) + pass1 (all blocks) ----
    if (bid < 128) {
        const int mtx = bid >> 6;          // 0: W0, 1: W1
        const int tidx = bid & 63;         // 8x8 tiles of 64x64
        const int i0 = (tidx >> 3) * 64, j0 = (tidx & 7) * 64;
        const void* W = mtx ? a.W1 : a.W0;
        __hip_bfloat16* Wt = mtx ? a.Wt1 : a.Wt0;
        const int rr = t >> 6, cc = t & 63;
#pragma unroll
        for (int it = 0; it < 16; ++it) {
            int ii = rr + it * 4;
            size_t idx = (size_t)(i0 + ii) * 512 + j0 + cc;   // coalesced over cc
            float v = isbf ? __bfloat162float(((const __hip_bfloat16*)W)[idx])
                           : ((const float*)W)[idx];
            sm.tile[ii][cc] = v;
        }
        __syncthreads();
#pragma unroll
        for (int it = 0; it < 16; ++it) {
            int jj = rr + it * 4;
            // read column (stride 65 -> conflict-free), write coalesced over cc
            Wt[(size_t)(j0 + jj) * 512 + i0 + cc] = __float2bfloat16(sm.tile[cc][jj]);
        }
        __syncthreads();   // union: tile -> pass.bm
    } else if (bid < 134) {
        int which = bid - 128;
        const void* p = (which == 0) ? a.sp0 : (which == 1) ? a.sp1 : (which == 2) ? a.sp2
                      : (which == 3) ? a.sp3 : (which == 4) ? a.sp4 : a.sp5;
#pragma unroll
        for (int r = 0; r < 2; ++r) {
            int e = t + r * 256;
            float v = isbf ? __bfloat162float(((const __hip_bfloat16*)p)[e])
                           : ((const float*)p)[e];
            a.smallc[which * 512 + e] = v;
        }
    } else if (bid == 134) {
        if (t < a.B) atomicMax(&a.mapId[a.ids[t]], t);   // max-t winner, matches sid loop
    }
    for (int i = t; i < 1568; i += 256) sm.pass.bm[i] = 0u;
    if (t < 16) sm.pass.sid[t] = (t < a.B) ? a.ids[t] : -1;
    if (t == 0) { sm.pass.eCnt = 0; sm.pass.fCnt = 0; }
    __syncthreads();
    if (t < a.B) { int n = sm.pass.sid[t]; atomicOr(&sm.pass.bm[n >> 5], 1u << (n & 31)); }
    __syncthreads();
    pass_scan<0>(a.src, a.dst, a.E, a.B, nullptr, sm.pass,
                 a.E1l, a.counters + 0, E1CAP, a.cnt1,
                 a.map1, a.F1list, a.counters + 2, C1CAP);
    gbar(a, ++gen);

    // ---- P1: pass2 (per-block LDS bitmap rebuilt from F1list) ----
    for (int i = t; i < 1568; i += 256) sm.pass.bm[i] = 0u;
    if (t == 0) { sm.pass.eCnt = 0; sm.pass.fCnt = 0; }
    __syncthreads();
    {
        int nf1 = a.counters[2]; if (nf1 > C1CAP) nf1 = C1CAP;
        for (int i = t; i < nf1; i += 256) {
            int n = a.F1list[i];
            atomicOr(&sm.pass.bm[n >> 5], 1u << (n & 31));
        }
    }
    __syncthreads();
    pass_scan<1>(a.src, a.dst, a.E, 0, a.map1, sm.pass,
                 a.E2l, a.counters + 1, E2CAP, a.cnt2,
                 a.map2, a.F2list, a.counters + 3, C2CAP);
    gbar(a, ++gen);

    // ---- P2: parallel scatter (every block, packed positions) + coalesced gather ----
    {
        int c0 = a.cnt2[t * 4 + 0], c1 = a.cnt2[t * 4 + 1];
        int c2 = a.cnt2[t * 4 + 2], c3 = a.cnt2[t * 4 + 3];
        int tsum = c0 + c1 + c2 + c3;
        sm.scat.sc[t] = tsum;
        __syncthreads();
        for (int off = 1; off < 256; off <<= 1) {
            int x = (t >= off) ? sm.scat.sc[t - off] : 0;
            __syncthreads();
            sm.scat.sc[t] += x;
            __syncthreads();
        }
        int run = sm.scat.sc[t] - tsum;
        int b4 = t * 4;
        sm.scat.soff[b4 + 0] = run; run += c0;
        sm.scat.soff[b4 + 1] = run; run += c1;
        sm.scat.soff[b4 + 2] = run; run += c2;
        sm.scat.soff[b4 + 3] = run; run += c3;
        if (t == 0) {
            int acc = 0;
            for (int i = 0; i < 16; ++i) { sm.scat.s1[i] = acc; acc += a.cnt1[i]; }
            if (bid == 0) {
                int a2 = 0;
                for (int i = 0; i < 16; ++i) { a.off1[i] = a2; a2 += a.cnt1[i]; }
                a.off1[16] = a2;
            }
        }
        if (bid == 0) {
#pragma unroll
            for (int k = 0; k < 4; ++k) a.off2[b4 + k] = sm.scat.soff[b4 + k];
            if (t == 255) a.off2[1024] = run;
        }
        __syncthreads();
        int n2 = a.counters[1]; if (n2 > E2CAP) n2 = E2CAP;
        for (int i = bid * 256 + t; i < n2; i += GA * 256) {
            int2 v = a.E2l[i];
            int y = v.y & 1023, p = v.y >> 10;
            int pos = sm.scat.soff[y] + p;
            int r = a.map2[v.x]; if (r < 0) r = 0;
            if (pos < E2CAP) a.b2[pos] = r;
        }
        int n1 = a.counters[0]; if (n1 > E1CAP) n1 = E1CAP;
        for (int i = bid * 256 + t; i < n1; i += GA * 256) {
            int2 v = a.E1l[i];
            int y = v.y & 15, p = v.y >> 4;
            int pos = sm.scat.s1[y] + p;
            int r = a.map1[v.x]; if (r < 0) r = 0;
            if (pos < E1CAP) a.b1[pos] = r;
        }
        // coalesced gather: one row per iteration, contiguous 1-2KB burst
        int cnt = a.counters[3]; if (cnt > C2CAP) cnt = C2CAP;
        for (int bb = bid; bb < cnt; bb += GA) {
            int row = a.F2list[bb];
            __hip_bfloat162 v;
            if (isbf) {
                v = *(const __hip_bfloat162*)&((const __hip_bfloat16*)a.features)[(size_t)row * KDIM + t * 2];
            } else {
                const float2 f = *(const float2*)&((const float*)a.features)[(size_t)row * KDIM + t * 2];
                v.x = __float2bfloat16(f.x);
                v.y = __float2bfloat16(f.y);
            }
            *(__hip_bfloat162*)&a.Ac[(size_t)bb * KDIM + t * 2] = v;
        }
    }
    gbar(a, ++gen);

    // ---- P3: gemm1 + el0/er0 ----
    {
        int cnt2v = a.counters[3]; if (cnt2v > C2CAP) cnt2v = C2CAP;
        int nt = ((cnt2v + 127) >> 7) * 4;
        for (int tile = bid; tile < nt; tile += GA)
            gemm_tile(a.Ac, a.Wt0, a.ft0c, a.smallc, a.smallc + 512,
                      a.el0, a.er0, cnt2v, (tile >> 2) * 128, (tile & 3) * 128, sm.gemm);
    }
    gbar(a, ++gen);

    // ---- P4: agg1 -> h1c (unroll-4 batched loads) ----
    {
        int cnt1v = a.counters[2]; if (cnt1v > C1CAP) cnt1v = C1CAP;
        const int h = t >> 6, lane = t & 63;
        for (int b = bid; b < cnt1v; b += GA) {
            int n = a.F1list[b];
            int rn = a.map2[n]; if (rn < 0) rn = 0;
            float ern = a.er0[rn * NHEAD + h];
            int beg = a.off2[b], end = a.off2[b + 1];
            float m = -3.0e38f, l = 0.f, a0 = 0.f, a1 = 0.f;
            int i = beg;
            for (; i + 4 <= end; i += 4) {
                int r4[4]; float ev[4]; __hip_bfloat162 fv[4];
#pragma unroll
                for (int k = 0; k < 4; ++k) {
                    int r = a.b2[i + k]; if ((unsigned)r >= C2CAP) r = 0;
                    r4[k] = r;
                }
#pragma unroll
                for (int k = 0; k < 4; ++k) {
                    ev[k] = a.el0[r4[k] * NHEAD + h];
                    fv[k] = *(const __hip_bfloat162*)&a.ft0c[(size_t)r4[k] * HD + h * DHEAD + lane * 2];
                }
#pragma unroll
                for (int k = 0; k < 4; ++k) {
                    float e = ev[k] + ern;
                    e = (e >= 0.f) ? e : 0.2f * e;
                    float mn = fmaxf(m, e);
                    float sc = __expf(m - mn);
                    float w  = __expf(e - mn);
                    l  = l * sc + w;
                    a0 = a0 * sc + w * __bfloat162float(fv[k].x);
                    a1 = a1 * sc + w * __bfloat162float(fv[k].y);
                    m = mn;
                }
            }
            for (; i < end; ++i) {
                int r2 = a.b2[i]; if ((unsigned)r2 >= C2CAP) r2 = 0;
                float e = a.el0[r2 * NHEAD + h] + ern;
                e = (e >= 0.f) ? e : 0.2f * e;
                float mn = fmaxf(m, e);
                float sc = __expf(m - mn);
                float w  = __expf(e - mn);
                const __hip_bfloat162 f = *(const __hip_bfloat162*)&a.ft0c[(size_t)r2 * HD + h * DHEAD + lane * 2];
                l  = l * sc + w;
                a0 = a0 * sc + w * __bfloat162float(f.x);
                a1 = a1 * sc + w * __bfloat162float(f.y);
                m = mn;
            }
            float inv = (l > 0.f) ? 1.0f / l : 0.f;
            float o0 = a0 * inv, o1 = a1 * inv;
            const float2 bb = *(const float2*)&a.smallc[1024 + h * DHEAD + lane * 2];
            o0 += bb.x; o1 += bb.y;
            o0 = (o0 > 0.f) ? o0 : expm1f(o0);
            o1 = (o1 > 0.f) ? o1 : expm1f(o1);
            __hip_bfloat162 o2;
            o2.x = __float2bfloat16(o0);
            o2.y = __float2bfloat16(o1);
            *(__hip_bfloat162*)&a.h1c[(size_t)b * HD + h * DHEAD + lane * 2] = o2;
        }
    }
    gbar(a, ++gen);

    // ---- P5: gemm2 + el1/er1 ----
    {
        int cnt1v = a.counters[2]; if (cnt1v > C1CAP) cnt1v = C1CAP;
        int nt = ((cnt1v + 127) >> 7) * 4;
        for (int tile = bid; tile < nt; tile += GA)
            gemm_tile(a.h1c, a.Wt1, a.ft1c, a.smallc + 1536, a.smallc + 2048,
                      a.el1, a.er1, cnt1v, (tile >> 2) * 128, (tile & 3) * 128, sm.gemm);
    }
    gbar(a, ++gen);

    // ---- P6: agg2 -> out ----
    if (bid < a.B) {
        const int b = bid;
        const int h = t >> 6, lane = t & 63;
        int n = a.ids[b];
        int slot = a.mapId[n]; if (slot < 0) slot = 0;
        int rn = a.map1[n]; if (rn < 0) rn = 0;
        float ern = a.er1[rn * NHEAD + h];
        int beg = a.off1[slot], end = a.off1[slot + 1];
        float m = -3.0e38f, l = 0.f, a0 = 0.f, a1 = 0.f;
        int i = beg;
        for (; i + 4 <= end; i += 4) {
            int r4[4]; float ev[4]; __hip_bfloat162 fv[4];
#pragma unroll
            for (int k = 0; k < 4; ++k) {
                int r = a.b1[i + k]; if ((unsigned)r >= C1CAP) r = 0;
                r4[k] = r;
            }
#pragma unroll
            for (int k = 0; k < 4; ++k) {
                ev[k] = a.el1[r4[k] * NHEAD + h];
                fv[k] = *(const __hip_bfloat162*)&a.ft1c[(size_t)r4[k] * HD + h * DHEAD + lane * 2];
            }
#pragma unroll
            for (int k = 0; k < 4; ++k) {
                float e = ev[k] + ern;
                e = (e >= 0.f) ? e : 0.2f * e;
                float mn = fmaxf(m, e);
                float sc = __expf(m - mn);
                float w  = __expf(e - mn);
                l  = l * sc + w;
                a0 = a0 * sc + w * __bfloat162float(fv[k].x);
                a1 = a1 * sc + w * __bfloat162float(fv[k].y);
                m = mn;
            }
        }
        for (; i < end; ++i) {
            int r1 = a.b1[i]; if ((unsigned)r1 >= C1CAP) r1 = 0;
            float e = a.el1[r1 * NHEAD + h] + ern;
            e = (e >= 0.f) ? e : 0.2f * e;
            float mn = fmaxf(m, e);
            float sc = __expf(m - mn);
            float w  = __expf(e - mn);
            const __hip_bfloat162 f = *(const __hip_bfloat162*)&a.ft1c[(size_t)r1 * HD + h * DHEAD + lane * 2];
            l  = l * sc + w;
            a0 = a0 * sc + w * __bfloat162float(f.x);
            a1 = a1 * sc + w * __bfloat162float(f.y);
            m = mn;
        }
        float inv = (l > 0.f) ? 1.0f / l : 0.f;
        float o0 = a0 * inv, o1 = a1 * inv;
        const __hip_bfloat162 rv = *(const __hip_bfloat162*)&a.h1c[(size_t)rn * HD + h * DHEAD + lane * 2];
        o0 += __bfloat162float(rv.x);
        o1 += __bfloat162float(rv.y);
        const float2 bb = *(const float2*)&a.smallc[2560 + h * DHEAD + lane * 2];
        o0 += bb.x; o1 += bb.y;
        o0 = (o0 > 0.f) ? o0 : expm1f(o0);
        o1 = (o1 > 0.f) ? o1 : expm1f(o1);
        o0 = tanhf(o0);
        o1 = tanhf(o1);
        size_t oi = (size_t)b * HD + h * DHEAD + lane * 2;
        if (isbf) {
            __hip_bfloat162 o2;
            o2.x = __float2bfloat16(o0);
            o2.y = __float2bfloat16(o1);
            *(__hip_bfloat162*)&((__hip_bfloat16*)a.out)[oi] = o2;
        } else {
            float2 o2; o2.x = o0; o2.y = o1;
            *(float2*)&((float*)a.out)[oi] = o2;
        }
    }
}

extern "C" void kernel_launch(void* const* d_in, const int* in_sizes, int n_in,
                              void* d_out, int out_size, void* d_ws, size_t ws_size,
                              hipStream_t stream) {
    const int N = in_sizes[0] / KDIM;   // 50000
    const int E = in_sizes[9];          // 1,650,000 (multiple of 4)
    const int B = in_sizes[11];         // 16

    char* w = (char*)d_ws;
    auto alloc = [&](size_t bytes) {
        void* p = (void*)w;
        w += (bytes + 255) & ~(size_t)255;
        return p;
    };
    __hip_bfloat16* Wt0 = (__hip_bfloat16*)alloc(512 * 512 * 2);
    __hip_bfloat16* Wt1 = (__hip_bfloat16*)alloc(512 * 512 * 2);
    float* smallc = (float*)alloc(6 * 512 * 4);
    int* maps  = (int*)alloc((size_t)3 * N * 4);   // mapId | map1 | map2, one memset
    int2* E1l  = (int2*)alloc((size_t)E1CAP * 8);
    int2* E2l  = (int2*)alloc((size_t)E2CAP * 8);
    int* F1list = (int*)alloc(C1CAP * 4);
    int* F2list = (int*)alloc(C2CAP * 4);
    // zeroed region: counters[8] | cnt1[16] | cnt2[1024] | arrive[GA] | rel[GA]
    const int zwords = 8 + 16 + 1024 + GA + GA;
    int* zmem = (int*)alloc((size_t)zwords * 4);
    int* counters = zmem;               // [0]nE1 [1]nE2 [2]nF1 [3]nF2
    int* cnt1 = zmem + 8;
    int* cnt2 = cnt1 + 16;
    int* arrive = cnt2 + 1024;
    int* rel    = arrive + GA;
    int* off1 = (int*)alloc(17 * 4);
    int* off2 = (int*)alloc(1025 * 4);
    int* b1   = (int*)alloc(E1CAP * 4);
    int* b2   = (int*)alloc(E2CAP * 4);
    __hip_bfloat16* Ac   = (__hip_bfloat16*)alloc((size_t)C2CAP * KDIM * 2);
    __hip_bfloat16* ft0c = (__hip_bfloat16*)alloc((size_t)C2CAP * HD * 2);
    float* el0 = (float*)alloc((size_t)C2CAP * NHEAD * 4);
    float* er0 = (float*)alloc((size_t)C2CAP * NHEAD * 4);
    __hip_bfloat16* h1c  = (__hip_bfloat16*)alloc((size_t)C1CAP * HD * 2);
    __hip_bfloat16* ft1c = (__hip_bfloat16*)alloc((size_t)C1CAP * HD * 2);
    float* el1 = (float*)alloc((size_t)C1CAP * NHEAD * 4);
    float* er1 = (float*)alloc((size_t)C1CAP * NHEAD * 4);

    hipMemsetAsync(maps, 0xFF, (size_t)3 * N * 4, stream);
    hipMemsetAsync(zmem, 0, (size_t)zwords * 4, stream);

    Args a;
    a.features = d_in[0];
    a.W0 = d_in[1]; a.W1 = d_in[5];
    a.Wt0 = Wt0; a.Wt1 = Wt1;
    a.sp0 = d_in[2]; a.sp1 = d_in[3]; a.sp2 = d_in[4];
    a.sp3 = d_in[6]; a.sp4 = d_in[7]; a.sp5 = d_in[8];
    a.smallc = smallc;
    a.ids = (const int*)d_in[11]; a.B = B;
    a.src = (const int*)d_in[9]; a.dst = (const int*)d_in[10]; a.E = E;
    a.mapId = maps; a.map1 = maps + N; a.map2 = maps + 2 * N;
    a.E1l = E1l; a.E2l = E2l; a.F1list = F1list; a.F2list = F2list;
    a.counters = counters; a.cnt1 = cnt1; a.cnt2 = cnt2;
    a.arrive = arrive; a.rel = rel;
    a.off1 = off1; a.off2 = off2; a.b1 = b1; a.b2 = b2;
    a.Ac = Ac; a.ft0c = ft0c; a.h1c = h1c; a.ft1c = ft1c;
    a.el0 = el0; a.er0 = er0; a.el1 = el1; a.er1 = er1;
    a.out = d_out;

    fused_all<<<GA, 256, 0, stream>>>(a);
}

// Round 11
// 330.019 us; speedup vs baseline: 1.1932x; 1.1932x over previous
//
#include <hip/hip_runtime.h>
#include <hip/hip_bf16.h>

typedef short bf16x8 __attribute__((ext_vector_type(8)));
typedef float f32x4 __attribute__((ext_vector_type(4)));

#define HD 512     // H*D
#define KDIM 512   // IN_DIM == H*D == 512
#define NHEAD 4
#define DHEAD 128
#define C1CAP 1024     // capacity for F1 = srcs(ids)   (~530)
#define C2CAP 16384    // capacity for F2 = srcs(F1)    (~14.8k)
#define E1CAP 2048     // edges into ids (~530)
#define E2CAP 32768    // edges into F1 (~17.5k)
#define SCATB 64       // parallel scatter blocks inside gathscat_k

struct PassSM {
    unsigned bm[1568];     // per-block node bitmap (N=50000 -> 1563 words)
    int2 eBuf[256];
    int fBuf[256];
    int sid[16];
    int eCnt, fCnt, eBase, fBase, s_c;
};

union PrepSM {
    PassSM pass;
    float tile[64][65];    // transpose tile (+1 pad -> conflict-free column reads)
    int s_c;
};

struct GemmSM {
    __hip_bfloat16 As[128][40];
    __hip_bfloat16 Bs[128][40];
    float pel[2][128];
    float perr[2][128];
};

// ---------------- per-block dtype detect (1 = bf16, 0 = f32) ----------------
__device__ int detect_bf16(const unsigned short* f, int* s_c) {
    int c = 0;
#pragma unroll
    for (int k = 0; k < 4; ++k) {
        unsigned short u = f[2 * (threadIdx.x + k * 256)];
        int e = (u >> 7) & 0xFF;
        c += (e >= 96 && e <= 140) ? 1 : 0;
    }
#pragma unroll
    for (int off = 32; off; off >>= 1) c += __shfl_xor(c, off, 64);
    if (threadIdx.x == 0) *s_c = 0;
    __syncthreads();
    if ((threadIdx.x & 63) == 0) atomicAdd(s_c, c);
    __syncthreads();
    int r = (*s_c > 512) ? 1 : 0;
    __syncthreads();
    return r;
}

// ---------------- BFS scan (LDS bitmap + block-buffered compaction) ----------------
// Emits edges with PACKED within-bucket position: v.y = slot | (p << SHIFT),
// so the scatter is cursor-free and embarrassingly parallel.
// MODE 0: slot = index of d in sid[] (pass 1).  MODE 1: slot = map1g[d].
template<int MODE>
__device__ void pass_scan(int pid, const int* __restrict__ src,
                          const int* __restrict__ dst, int E, int B,
                          const int* __restrict__ map1g, PassSM& sm,
                          int2* __restrict__ elist, int* ecnt, int ecap,
                          int* __restrict__ cntArr,
                          int* __restrict__ mapm, int* __restrict__ Flist,
                          int* nFr, int fcap) {
    const int t = threadIdx.x;
    const int nq = E >> 2;   // E % 4 == 0
    const int gid = pid * 256 + t;
    if (gid < nq) {
        const int4 d4 = ((const int4*)dst)[gid];
        const int dv[4] = {d4.x, d4.y, d4.z, d4.w};
#pragma unroll
        for (int k = 0; k < 4; ++k) {
            const int d = dv[k];
            if ((sm.bm[d >> 5] >> (d & 31)) & 1u) {
                const int e = 4 * gid + k;
                int slot;
                if (MODE == 0) {
                    slot = 0;
                    for (int q = 0; q < B; ++q) if (sm.sid[q] == d) slot = q;
                } else {
                    slot = map1g[d]; if (slot < 0) slot = 0;
                }
                int p = atomicAdd(&cntArr[slot], 1);   // position within bucket
                int2 v; v.x = src[e]; v.y = slot | (p << (MODE == 0 ? 4 : 10));
                int pp = atomicAdd(&sm.eCnt, 1);
                if (pp < 256) sm.eBuf[pp] = v;
                else { int q = atomicAdd(ecnt, 1); if (q < ecap) elist[q] = v; }
                const int s = v.x;
                if (atomicCAS(&mapm[s], -1, -2) == -1) {
                    int q = atomicAdd(&sm.fCnt, 1);
                    if (q < 256) sm.fBuf[q] = s;
                    else {
                        int g2 = atomicAdd(nFr, 1);
                        if (g2 < fcap) { Flist[g2] = s; mapm[s] = g2; }
                        else mapm[s] = 0;
                    }
                }
            }
        }
    }
    __syncthreads();
    const int ne = (sm.eCnt < 256) ? sm.eCnt : 256;
    const int nf = (sm.fCnt < 256) ? sm.fCnt : 256;
    if (t == 0 && ne) sm.eBase = atomicAdd(ecnt, ne);
    if (t == 64 && nf) sm.fBase = atomicAdd(nFr, nf);
    __syncthreads();
    for (int i = t; i < ne; i += 256) {
        int pos = sm.eBase + i;
        if (pos < ecap) elist[pos] = sm.eBuf[i];
    }
    for (int i = t; i < nf; i += 256) {
        int q = sm.fBase + i; int s = sm.fBuf[i];
        if (q < fcap) { Flist[q] = s; mapm[s] = q; }
        else mapm[s] = 0;
    }
}

// ---------------- GEMM tile + fused el/er epilogue, 2-DEEP reg prefetch ----------------
// R10 post-mortem: 1-deep prefetch covers ~350cyc but A-loads take ~600-900cyc
// (Ac spans XCDs). Two in-flight K-steps (static-indexed a0/b0, a1/b1 -- no
// runtime array index, rule-#20-safe) give ~2 K-steps of cover.
__device__ void gemm_tile(const __hip_bfloat16* __restrict__ A,
                          const __hip_bfloat16* __restrict__ Bt,
                          __hip_bfloat16* __restrict__ C,
                          const float* __restrict__ al_, const float* __restrict__ ar_,
                          float* __restrict__ el, float* __restrict__ er,
                          int cntv, int m0, int n0, GemmSM& sm) {
    const int t = threadIdx.x;
    const int lane = t & 63, wave = t >> 6;
    const int wm = (wave >> 1) * 64, wn = (wave & 1) * 64;
    const int fr = lane & 15, fk = (lane >> 4) * 8;
    const int r0 = t >> 2;
    const int c0 = (t & 3) * 8;

    int arow[2];
#pragma unroll
    for (int r = 0; r < 2; ++r) {
        int rr = m0 + r * 64 + r0;
        if (rr >= cntv) rr = cntv - 1;
        arow[r] = rr;
    }

    auto loadAB = [&](int kt, uint4 va[2], uint4 vb[2]) {
#pragma unroll
        for (int r = 0; r < 2; ++r) {
            va[r] = *(const uint4*)&A[(size_t)arow[r] * KDIM + kt + c0];
            int row = r * 64 + r0;
            vb[r] = *(const uint4*)&Bt[(size_t)(n0 + row) * KDIM + kt + c0];
        }
    };

    f32x4 acc[4][4];
#pragma unroll
    for (int i = 0; i < 4; ++i)
#pragma unroll
        for (int j = 0; j < 4; ++j)
#pragma unroll
            for (int r = 0; r < 4; ++r) acc[i][j][r] = 0.f;

    auto stepStore = [&](uint4 va[2], uint4 vb[2]) {
#pragma unroll
        for (int r = 0; r < 2; ++r) {
            int row = r * 64 + r0;
            *(uint4*)&sm.As[row][c0] = va[r];
            *(uint4*)&sm.Bs[row][c0] = vb[r];
        }
        __syncthreads();
    };
    auto stepCompute = [&]() {
        bf16x8 af[4], bfr[4];
#pragma unroll
        for (int i = 0; i < 4; ++i) af[i]  = *(const bf16x8*)&sm.As[wm + i * 16 + fr][fk];
#pragma unroll
        for (int j = 0; j < 4; ++j) bfr[j] = *(const bf16x8*)&sm.Bs[wn + j * 16 + fr][fk];
#pragma unroll
        for (int i = 0; i < 4; ++i)
#pragma unroll
            for (int j = 0; j < 4; ++j)
                acc[i][j] = __builtin_amdgcn_mfma_f32_16x16x32_bf16(af[i], bfr[j], acc[i][j], 0, 0, 0);
        __syncthreads();
    };

    uint4 a0[2], b0[2], a1[2], b1[2];
    loadAB(0, a0, b0);
    loadAB(32, a1, b1);
    for (int kt = 0; kt < KDIM; kt += 64) {
        stepStore(a0, b0);
        if (kt + 64 < KDIM) loadAB(kt + 64, a0, b0);   // lands 2 K-steps later
        stepCompute();
        stepStore(a1, b1);
        if (kt + 96 < KDIM) loadAB(kt + 96, a1, b1);
        stepCompute();
    }

    const int cr = (lane >> 4) * 4;
    const int cc = lane & 15;
#pragma unroll
    for (int i = 0; i < 4; ++i)
#pragma unroll
        for (int j = 0; j < 4; ++j)
#pragma unroll
            for (int rg = 0; rg < 4; ++rg) {
                int m = m0 + wm + i * 16 + cr + rg;
                int n = n0 + wn + j * 16 + cc;
                C[(size_t)m * HD + n] = __float2bfloat16(acc[i][j][rg]);
            }

    // fused el/er (head h = n0>>7; block owns the full head slice of these rows)
    const int h = n0 >> 7;
    float alv[4], arv[4];
#pragma unroll
    for (int j = 0; j < 4; ++j) {
        alv[j] = al_[h * DHEAD + wn + j * 16 + cc];
        arv[j] = ar_[h * DHEAD + wn + j * 16 + cc];
    }
#pragma unroll
    for (int i = 0; i < 4; ++i)
#pragma unroll
        for (int rg = 0; rg < 4; ++rg) {
            float sl = 0.f, sr = 0.f;
#pragma unroll
            for (int j = 0; j < 4; ++j) {
                float c = acc[i][j][rg];
                sl += c * alv[j];
                sr += c * arv[j];
            }
#pragma unroll
            for (int off = 1; off < 16; off <<= 1) {
                sl += __shfl_xor(sl, off, 16);
                sr += __shfl_xor(sr, off, 16);
            }
            if (cc == 0) {
                int row = wm + i * 16 + cr + rg;
                sm.pel[wn >> 6][row] = sl;
                sm.perr[wn >> 6][row] = sr;
            }
        }
    __syncthreads();
    if (t < 128) {
        int m = m0 + t;
        if (m < cntv) {
            el[m * NHEAD + h] = sm.pel[0][t] + sm.pel[1][t];
            er[m * NHEAD + h] = sm.perr[0][t] + sm.perr[1][t];
        }
    }
    __syncthreads();   // protect pel/perr (and As/Bs) before next tile
}

// ---------------- K1: prep (LDS-tiled transpose/smalls/setid) + pass1 fused ----------------
__global__ __launch_bounds__(256) void prep_pass1_k(
    const void* __restrict__ features,
    const void* __restrict__ W0, const void* __restrict__ W1,
    __hip_bfloat16* __restrict__ Wt0, __hip_bfloat16* __restrict__ Wt1,
    const void* p0, const void* p1, const void* p2,
    const void* p3, const void* p4, const void* p5,
    float* __restrict__ smallc,
    const int* __restrict__ ids, int B, int* __restrict__ mapId,
    const int* __restrict__ src, const int* __restrict__ dst, int E,
    int2* __restrict__ E1l, int* __restrict__ counters,
    int* __restrict__ cnt1, int* __restrict__ map1, int* __restrict__ F1list) {
    __shared__ PrepSM sm;
    const int b = blockIdx.x;
    const int t = threadIdx.x;
    if (b < 128) {
        const int isbf = detect_bf16((const unsigned short*)features, &sm.s_c);
        const int mtx = b >> 6;            // 0: W0, 1: W1
        const int tidx = b & 63;           // 8x8 tiles of 64x64
        const int i0 = (tidx >> 3) * 64, j0 = (tidx & 7) * 64;
        const void* W = mtx ? W1 : W0;
        __hip_bfloat16* Wt = mtx ? Wt1 : Wt0;
        const int rr = t >> 6, cc = t & 63;
#pragma unroll
        for (int it = 0; it < 16; ++it) {
            int ii = rr + it * 4;
            size_t idx = (size_t)(i0 + ii) * 512 + j0 + cc;   // coalesced over cc
            float v = isbf ? __bfloat162float(((const __hip_bfloat16*)W)[idx])
                           : ((const float*)W)[idx];
            sm.tile[ii][cc] = v;
        }
        __syncthreads();
#pragma unroll
        for (int it = 0; it < 16; ++it) {
            int jj = rr + it * 4;
            // read column (stride 65 -> conflict-free), write coalesced over cc
            Wt[(size_t)(j0 + jj) * 512 + i0 + cc] = __float2bfloat16(sm.tile[cc][jj]);
        }
    } else if (b < 134) {
        const int isbf = detect_bf16((const unsigned short*)features, &sm.s_c);
        int which = b - 128;
        const void* p;
        switch (which) {
            case 0: p = p0; break;
            case 1: p = p1; break;
            case 2: p = p2; break;
            case 3: p = p3; break;
            case 4: p = p4; break;
            default: p = p5; break;
        }
#pragma unroll
        for (int r = 0; r < 2; ++r) {
            int e = t + r * 256;
            float v = isbf ? __bfloat162float(((const __hip_bfloat16*)p)[e])
                           : ((const float*)p)[e];
            smallc[which * 512 + e] = v;
        }
    } else if (b == 134) {
        if (t < B) atomicMax(&mapId[ids[t]], t);   // max-t winner, matches sid loop
    } else {
        const int pid = b - 135;
        for (int i = t; i < 1568; i += 256) sm.pass.bm[i] = 0u;
        if (t < 16) sm.pass.sid[t] = (t < B) ? ids[t] : -1;
        if (t == 0) { sm.pass.eCnt = 0; sm.pass.fCnt = 0; }
        __syncthreads();
        if (t < B) { int n = sm.pass.sid[t]; atomicOr(&sm.pass.bm[n >> 5], 1u << (n & 31)); }
        __syncthreads();
        pass_scan<0>(pid, src, dst, E, B, nullptr, sm.pass,
                     E1l, counters + 0, E1CAP, cnt1,
                     map1, F1list, counters + 2, C1CAP);
    }
}

// ---------------- K2: pass2 (per-block LDS bitmap rebuilt from F1list) ----------------
__global__ __launch_bounds__(256) void pass2_k(
    const int* __restrict__ src, const int* __restrict__ dst, int E,
    const int* __restrict__ F1list, int* __restrict__ counters,
    const int* __restrict__ map1,
    int2* __restrict__ E2l, int* __restrict__ cnt2,
    int* __restrict__ map2, int* __restrict__ F2list) {
    __shared__ PassSM sm;
    const int t = threadIdx.x;
    for (int i = t; i < 1568; i += 256) sm.bm[i] = 0u;
    if (t == 0) { sm.eCnt = 0; sm.fCnt = 0; }
    __syncthreads();
    int nf1 = counters[2]; if (nf1 > C1CAP) nf1 = C1CAP;
    for (int i = t; i < nf1; i += 256) {
        int n = F1list[i];
        atomicOr(&sm.bm[n >> 5], 1u << (n & 31));
    }
    __syncthreads();
    pass_scan<1>(blockIdx.x, src, dst, E, 0, map1, sm,
                 E2l, counters + 1, E2CAP, cnt2,
                 map2, F2list, counters + 3, C2CAP);
}

// ---------------- G: gather (blocks SCATB..) + PARALLEL scatter (blocks 0..SCATB-1) ----
__global__ __launch_bounds__(256) void gathscat_k(
    const void* __restrict__ feat, const int* __restrict__ F2list,
    const int* __restrict__ counters,
    const int* __restrict__ cnt1, const int* __restrict__ cnt2,
    const int2* __restrict__ E1l, const int2* __restrict__ E2l,
    const int* __restrict__ map1, const int* __restrict__ map2,
    int* __restrict__ off1, int* __restrict__ off2,
    int* __restrict__ b1, int* __restrict__ b2,
    __hip_bfloat16* __restrict__ Ac) {
    __shared__ int soff[1024];
    __shared__ int sc[256];
    __shared__ int s1[16];
    __shared__ int s_c;
    const int t = threadIdx.x;
    const int b = blockIdx.x;
    if (b < SCATB) {
        int c0 = cnt2[t * 4 + 0], c1 = cnt2[t * 4 + 1];
        int c2 = cnt2[t * 4 + 2], c3 = cnt2[t * 4 + 3];
        int tsum = c0 + c1 + c2 + c3;
        sc[t] = tsum;
        __syncthreads();
        for (int off = 1; off < 256; off <<= 1) {
            int x = (t >= off) ? sc[t - off] : 0;
            __syncthreads();
            sc[t] += x;
            __syncthreads();
        }
        int run = sc[t] - tsum;
        int b4 = t * 4;
        soff[b4 + 0] = run; run += c0;
        soff[b4 + 1] = run; run += c1;
        soff[b4 + 2] = run; run += c2;
        soff[b4 + 3] = run; run += c3;
        if (t == 0) {
            int acc = 0;
            for (int i = 0; i < 16; ++i) { s1[i] = acc; acc += cnt1[i]; }
            if (b == 0) {
                int a2 = 0;
                for (int i = 0; i < 16; ++i) { off1[i] = a2; a2 += cnt1[i]; }
                off1[16] = a2;
            }
        }
        if (b == 0) {
#pragma unroll
            for (int k = 0; k < 4; ++k) off2[b4 + k] = soff[b4 + k];
            if (t == 255) off2[1024] = run;
        }
        __syncthreads();
        int n2 = counters[1]; if (n2 > E2CAP) n2 = E2CAP;
        for (int i = b * 256 + t; i < n2; i += SCATB * 256) {
            int2 v = E2l[i];
            int y = v.y & 1023, p = v.y >> 10;
            int pos = soff[y] + p;
            int r = map2[v.x]; if (r < 0) r = 0;
            if (pos < E2CAP) b2[pos] = r;
        }
        int n1 = counters[0]; if (n1 > E1CAP) n1 = E1CAP;
        for (int i = b * 256 + t; i < n1; i += SCATB * 256) {
            int2 v = E1l[i];
            int y = v.y & 15, p = v.y >> 4;
            int pos = s1[y] + p;
            int r = map1[v.x]; if (r < 0) r = 0;
            if (pos < E1CAP) b1[pos] = r;
        }
    } else {
        const int isbf = detect_bf16((const unsigned short*)feat, &s_c);
        int cnt = counters[3]; if (cnt > C2CAP) cnt = C2CAP;
        for (int bb = b - SCATB; bb < cnt; bb += (int)gridDim.x - SCATB) {
            int row = F2list[bb];
            __hip_bfloat162 v;
            if (isbf) {
                v = *(const __hip_bfloat162*)&((const __hip_bfloat16*)feat)[(size_t)row * KDIM + t * 2];
            } else {
                const float2 f = *(const float2*)&((const float*)feat)[(size_t)row * KDIM + t * 2];
                v.x = __float2bfloat16(f.x);
                v.y = __float2bfloat16(f.y);
            }
            *(__hip_bfloat162*)&Ac[(size_t)bb * KDIM + t * 2] = v;
        }
    }
}

// ---------------- K3/K5: pure GEMM (+fused el/er), XCD-aware tile mapping ----------------
// bid -> (panel p, col j) with p = (s>>2)*8 + xcd, j = s&3: the 4 column-tiles
// of each 128-row A-panel land on the SAME XCD (bid&7 heuristic) -> A fetched
// once per panel instead of 4x across non-coherent L2s (R10: ~45MB re-fetch).
// Grid must be a multiple of 32.
__global__ __launch_bounds__(256) void gemmel_k(
    const __hip_bfloat16* __restrict__ A,
    const __hip_bfloat16* __restrict__ Bt, __hip_bfloat16* __restrict__ C,
    const float* __restrict__ al_, const float* __restrict__ ar_,
    float* __restrict__ el, float* __restrict__ er,
    const int* __restrict__ countp, int cap) {
    __shared__ alignas(16) GemmSM sm;
    int cntv = *countp; if (cntv > cap) cntv = cap;
    const int nP = (cntv + 127) >> 7;
    const int xcd = blockIdx.x & 7;
    const int s = blockIdx.x >> 3;
    const int j = s & 3;
    const int perXcd = (int)gridDim.x >> 3;
    const int pstride = (perXcd >> 2) * 8;
    for (int p = (s >> 2) * 8 + xcd; p < nP; p += pstride)
        gemm_tile(A, Bt, C, al_, ar_, el, er, cntv, p * 128, j * 128, sm);
}

// ---------------- K4: agg1 (unroll-8 batched loads) ----------------
__global__ __launch_bounds__(256) void agg1_k(
    const int* __restrict__ off2, const int* __restrict__ b2,
    const int* __restrict__ F1list, const int* __restrict__ map2,
    const int* __restrict__ nF1p,
    const float* __restrict__ el, const float* __restrict__ er,
    const __hip_bfloat16* __restrict__ ftc,
    const float* __restrict__ bias,
    __hip_bfloat16* __restrict__ outc) {
    int b = blockIdx.x;
    if (b >= *nF1p) return;
    int n = F1list[b];
    const int h = threadIdx.x >> 6, lane = threadIdx.x & 63;
    int rn = map2[n]; if (rn < 0) rn = 0;
    float ern = er[rn * NHEAD + h];
    int beg = off2[b], end = off2[b + 1];
    float m = -3.0e38f, l = 0.f, a0 = 0.f, a1 = 0.f;
    int i = beg;
    for (; i + 8 <= end; i += 8) {
        int r8[8]; float ev[8]; __hip_bfloat162 fv[8];
#pragma unroll
        for (int k = 0; k < 8; ++k) {
            int r = b2[i + k]; if ((unsigned)r >= C2CAP) r = 0;
            r8[k] = r;
        }
#pragma unroll
        for (int k = 0; k < 8; ++k) {     // 16 independent loads in flight
            ev[k] = el[r8[k] * NHEAD + h];
            fv[k] = *(const __hip_bfloat162*)&ftc[(size_t)r8[k] * HD + h * DHEAD + lane * 2];
        }
#pragma unroll
        for (int k = 0; k < 8; ++k) {
            float e = ev[k] + ern;
            e = (e >= 0.f) ? e : 0.2f * e;
            float mn = fmaxf(m, e);
            float sc = __expf(m - mn);
            float w  = __expf(e - mn);
            l  = l * sc + w;
            a0 = a0 * sc + w * __bfloat162float(fv[k].x);
            a1 = a1 * sc + w * __bfloat162float(fv[k].y);
            m = mn;
        }
    }
    for (; i < end; ++i) {
        int r2 = b2[i]; if ((unsigned)r2 >= C2CAP) r2 = 0;
        float e = el[r2 * NHEAD + h] + ern;
        e = (e >= 0.f) ? e : 0.2f * e;
        float mn = fmaxf(m, e);
        float sc = __expf(m - mn);
        float w  = __expf(e - mn);
        const __hip_bfloat162 f = *(const __hip_bfloat162*)&ftc[(size_t)r2 * HD + h * DHEAD + lane * 2];
        l  = l * sc + w;
        a0 = a0 * sc + w * __bfloat162float(f.x);
        a1 = a1 * sc + w * __bfloat162float(f.y);
        m = mn;
    }
    float inv = (l > 0.f) ? 1.0f / l : 0.f;
    float o0 = a0 * inv, o1 = a1 * inv;
    const float2 bb = *(const float2*)&bias[h * DHEAD + lane * 2];
    o0 += bb.x; o1 += bb.y;
    o0 = (o0 > 0.f) ? o0 : expm1f(o0);
    o1 = (o1 > 0.f) ? o1 : expm1f(o1);
    __hip_bfloat162 o2;
    o2.x = __float2bfloat16(o0);
    o2.y = __float2bfloat16(o1);
    *(__hip_bfloat162*)&outc[(size_t)b * HD + h * DHEAD + lane * 2] = o2;
}

// ---------------- K6: agg2 (unroll-8) ----------------
__global__ __launch_bounds__(256) void agg2_k(
    const int* __restrict__ off1, const int* __restrict__ b1,
    const int* __restrict__ ids, const int* __restrict__ mapId,
    const int* __restrict__ map1,
    const float* __restrict__ el, const float* __restrict__ er,
    const __hip_bfloat16* __restrict__ ftc,
    const __hip_bfloat16* __restrict__ resc,
    const float* __restrict__ bias,
    void* __restrict__ out, const void* __restrict__ features) {
    __shared__ int s_c;
    const int isbf = detect_bf16((const unsigned short*)features, &s_c);
    int b = blockIdx.x;
    int n = ids[b];
    int slot = mapId[n]; if (slot < 0) slot = 0;
    const int h = threadIdx.x >> 6, lane = threadIdx.x & 63;
    int rn = map1[n]; if (rn < 0) rn = 0;
    float ern = er[rn * NHEAD + h];
    int beg = off1[slot], end = off1[slot + 1];
    float m = -3.0e38f, l = 0.f, a0 = 0.f, a1 = 0.f;
    int i = beg;
    for (; i + 8 <= end; i += 8) {
        int r8[8]; float ev[8]; __hip_bfloat162 fv[8];
#pragma unroll
        for (int k = 0; k < 8; ++k) {
            int r = b1[i + k]; if ((unsigned)r >= C1CAP) r = 0;
            r8[k] = r;
        }
#pragma unroll
        for (int k = 0; k < 8; ++k) {
            ev[k] = el[r8[k] * NHEAD + h];
            fv[k] = *(const __hip_bfloat162*)&ftc[(size_t)r8[k] * HD + h * DHEAD + lane * 2];
        }
#pragma unroll
        for (int k = 0; k < 8; ++k) {
            float e = ev[k] + ern;
            e = (e >= 0.f) ? e : 0.2f * e;
            float mn = fmaxf(m, e);
            float sc = __expf(m - mn);
            float w  = __expf(e - mn);
            l  = l * sc + w;
            a0 = a0 * sc + w * __bfloat162float(fv[k].x);
            a1 = a1 * sc + w * __bfloat162float(fv[k].y);
            m = mn;
        }
    }
    for (; i < end; ++i) {
        int r1 = b1[i]; if ((unsigned)r1 >= C1CAP) r1 = 0;
        float e = el[r1 * NHEAD + h] + ern;
        e = (e >= 0.f) ? e : 0.2f * e;
        float mn = fmaxf(m, e);
        float sc = __expf(m - mn);
        float w  = __expf(e - mn);
        const __hip_bfloat162 f = *(const __hip_bfloat162*)&ftc[(size_t)r1 * HD + h * DHEAD + lane * 2];
        l  = l * sc + w;
        a0 = a0 * sc + w * __bfloat162float(f.x);
        a1 = a1 * sc + w * __bfloat162float(f.y);
        m = mn;
    }
    float inv = (l > 0.f) ? 1.0f / l : 0.f;
    float o0 = a0 * inv, o1 = a1 * inv;
    const __hip_bfloat162 rv = *(const __hip_bfloat162*)&resc[(size_t)rn * HD + h * DHEAD + lane * 2];
    o0 += __bfloat162float(rv.x);
    o1 += __bfloat162float(rv.y);
    const float2 bb = *(const float2*)&bias[h * DHEAD + lane * 2];
    o0 += bb.x; o1 += bb.y;
    o0 = (o0 > 0.f) ? o0 : expm1f(o0);
    o1 = (o1 > 0.f) ? o1 : expm1f(o1);
    o0 = tanhf(o0);
    o1 = tanhf(o1);
    size_t oi = (size_t)b * HD + h * DHEAD + lane * 2;
    if (isbf) {
        __hip_bfloat162 o2;
        o2.x = __float2bfloat16(o0);
        o2.y = __float2bfloat16(o1);
        *(__hip_bfloat162*)&((__hip_bfloat16*)out)[oi] = o2;
    } else {
        float2 o2; o2.x = o0; o2.y = o1;
        *(float2*)&((float*)out)[oi] = o2;
    }
}

extern "C" void kernel_launch(void* const* d_in, const int* in_sizes, int n_in,
                              void* d_out, int out_size, void* d_ws, size_t ws_size,
                              hipStream_t stream) {
    const void* features = d_in[0];
    const int* src = (const int*)d_in[9];
    const int* dst = (const int*)d_in[10];
    const int* ids = (const int*)d_in[11];

    const int N = in_sizes[0] / KDIM;   // 50000
    const int E = in_sizes[9];          // 1,650,000 (multiple of 4)
    const int B = in_sizes[11];         // 16

    char* w = (char*)d_ws;
    auto alloc = [&](size_t bytes) {
        void* p = (void*)w;
        w += (bytes + 255) & ~(size_t)255;
        return p;
    };
    __hip_bfloat16* Wt0 = (__hip_bfloat16*)alloc(512 * 512 * 2);
    __hip_bfloat16* Wt1 = (__hip_bfloat16*)alloc(512 * 512 * 2);
    float* smallc = (float*)alloc(6 * 512 * 4);
    int* maps  = (int*)alloc((size_t)3 * N * 4);   // mapId | map1 | map2, one memset
    int* mapId = maps;
    int* map1  = maps + N;
    int* map2  = maps + 2 * N;
    int2* E1l  = (int2*)alloc((size_t)E1CAP * 8);
    int2* E2l  = (int2*)alloc((size_t)E2CAP * 8);
    int* F1list = (int*)alloc(C1CAP * 4);
    int* F2list = (int*)alloc(C2CAP * 4);
    // zeroed region: counters[8] | cnt1[16] | cnt2[1024]
    const int zwords = 8 + 16 + 1024;
    int* zmem = (int*)alloc((size_t)zwords * 4);
    int* counters = zmem;               // [0]nE1 [1]nE2 [2]nF1 [3]nF2
    int* cnt1 = zmem + 8;
    int* cnt2 = cnt1 + 16;
    int* off1 = (int*)alloc(17 * 4);
    int* off2 = (int*)alloc(1025 * 4);
    int* b1   = (int*)alloc(E1CAP * 4);
    int* b2   = (int*)alloc(E2CAP * 4);
    __hip_bfloat16* Ac   = (__hip_bfloat16*)alloc((size_t)C2CAP * KDIM * 2);
    __hip_bfloat16* ft0c = (__hip_bfloat16*)alloc((size_t)C2CAP * HD * 2);
    float* el0 = (float*)alloc((size_t)C2CAP * NHEAD * 4);
    float* er0 = (float*)alloc((size_t)C2CAP * NHEAD * 4);
    __hip_bfloat16* h1c  = (__hip_bfloat16*)alloc((size_t)C1CAP * HD * 2);
    __hip_bfloat16* ft1c = (__hip_bfloat16*)alloc((size_t)C1CAP * HD * 2);
    float* el1 = (float*)alloc((size_t)C1CAP * NHEAD * 4);
    float* er1 = (float*)alloc((size_t)C1CAP * NHEAD * 4);

    hipMemsetAsync(maps, 0xFF, (size_t)3 * N * 4, stream);
    hipMemsetAsync(zmem, 0, (size_t)zwords * 4, stream);

    float* al0c = smallc + 0 * 512;
    float* ar0c = smallc + 1 * 512;
    float* b0c  = smallc + 2 * 512;
    float* al1c = smallc + 3 * 512;
    float* ar1c = smallc + 4 * 512;
    float* b1c  = smallc + 5 * 512;

    const int nblk_scan = (E / 4 + 255) / 256;   // 1612

    // K1: prep (tiled transpose) + pass1 fused
    prep_pass1_k<<<135 + nblk_scan, 256, 0, stream>>>(
        features, d_in[1], d_in[5], Wt0, Wt1,
        d_in[2], d_in[3], d_in[4], d_in[6], d_in[7], d_in[8],
        smallc, ids, B, mapId, src, dst, E,
        E1l, counters, cnt1, map1, F1list);

    // K2: pass2 (per-block LDS bitmap from F1list)
    pass2_k<<<nblk_scan, 256, 0, stream>>>(src, dst, E, F1list, counters, map1,
                                           E2l, cnt2, map2, F2list);

    // G: parallel scatter (blocks 0..63) + coalesced gather -> Ac (blocks 64..)
    gathscat_k<<<2048, 256, 0, stream>>>(features, F2list, counters, cnt1, cnt2,
                                         E1l, E2l, map1, map2,
                                         off1, off2, b1, b2, Ac);

    // K3: gemm1 + el0/er0 (XCD-aware panel mapping; grid multiple of 32)
    gemmel_k<<<512, 256, 0, stream>>>(Ac, Wt0, ft0c, al0c, ar0c, el0, er0,
                                      counters + 3, C2CAP);

    // K4: agg1 -> h1c
    agg1_k<<<C1CAP, 256, 0, stream>>>(off2, b2, F1list, map2, counters + 2,
                                      el0, er0, ft0c, b0c, h1c);

    // K5: gemm2 + el1/er1 (grid 32: p = xcd, j = s covers 8 panels x 4 cols)
    gemmel_k<<<32, 256, 0, stream>>>(h1c, Wt1, ft1c, al1c, ar1c, el1, er1,
                                     counters + 2, C1CAP);

    // K6: agg2 -> out
    agg2_k<<<B, 256, 0, stream>>>(off1, b1, ids, mapId, map1,
                                  el1, er1, ft1c, h1c, b1c,
                                  d_out, features);
}